// Round 12
// baseline (134.757 us; speedup 1.0000x reference)
//
#include <hip/hip_runtime.h>
#include <hip/hip_fp16.h>

// Reblur_Net: 3 recurrent modulated DCNv2 passes, C=O=3, K=3, B=4, H=W=512.
// out = (sharp + f1 + f2 + f3) / 4.
//
// Key structure: the bilinear address+weight computation depends only on
// `motion` and is IDENTICAL in all 3 passes -> compute it ONCE in prep.
//  prep : per 256-px strip, DMA fp32 motion (27KB) to LDS, compute per
//         pixel/tap the packed gather offset + 4 blended fp16 weights
//         (modulation folded in); store 12 B/px/tap (27.6 KB/strip).
//         Also converts sharp -> half4.
//  pass : DMA the 27.6 KB tap block to LDS; per tap: 3 ds_reads + decode +
//         2 x dwordx4 feature gathers + FMAs. No floor/clamp/validity work.
//         Pass 3 folds the 4-way average.

#define HH 512
#define WW 512
#define BATCH 4
#define HWSZ (HH * WW)
#define NSTRIP 4096                 // strips of 256 px
#define TAPB 27648                  // bytes per strip tap block (9*1024*3)

union U4 { uint4 u; __half2 h[4]; };
union U2 { uint2 u; __half2 h[2]; };

typedef const __attribute__((address_space(1))) void* gas_t;
typedef __attribute__((address_space(3))) void* las_t;

// prep: blocks 0..4095 = tap-gen per strip; 4096..6143 = sharp -> half4.
__global__ __launch_bounds__(256) void prep_kernel(
    const float* __restrict__ sharp, const float* __restrict__ motion,
    uint4* __restrict__ sharp16, char* __restrict__ taps)
{
    __shared__ __align__(16) char msmem[27 * 1024];
    const int t = threadIdx.x;
    const int blk = blockIdx.x;

    if (blk >= NSTRIP) {
        // sharp [B,3,H,W] fp32 -> half4 px pairs.
        const int i = (blk - NSTRIP) * 256 + t;     // pair index, 524288 total
        const int b = i >> 17;
        const int p = (i & (HWSZ / 2 - 1)) * 2;
        const float* s = sharp + (size_t)b * 3 * HWSZ + p;
        const float2 c0 = *(const float2*)(s);
        const float2 c1 = *(const float2*)(s + HWSZ);
        const float2 c2 = *(const float2*)(s + 2 * HWSZ);
        U4 o;
        o.h[0] = __float22half2_rn(make_float2(c0.x, c1.x));
        o.h[1] = __float22half2_rn(make_float2(c2.x, 0.f));
        o.h[2] = __float22half2_rn(make_float2(c0.y, c1.y));
        o.h[3] = __float22half2_rn(make_float2(c2.y, 0.f));
        sharp16[i] = o.u;
        return;
    }

    const int b = blk >> 10;
    const int pbase = (blk & 1023) * 256;
    const int y = pbase >> 9;
    const int x = (pbase & 511) + t;
    const int w = t >> 6, lane = t & 63;

    // DMA fp32 motion strip -> LDS (27 planes x 1024 B).
    {
        const float* mbase = motion + (size_t)b * 27 * HWSZ + pbase;
#pragma unroll
        for (int r = 0; r < 7; ++r) {
            const int pl = r * 4 + w;
            if (pl < 27) {
                __builtin_amdgcn_global_load_lds((gas_t)(mbase + (size_t)pl * HWSZ + lane * 4),
                                                 (las_t)(msmem + pl * 1024),
                                                 16, 0, 0);
            }
        }
    }
    __syncthreads();

    const float* mf = (const float*)msmem;
    char* tb = taps + (size_t)blk * TAPB;

#pragma unroll
    for (int k = 0; k < 9; ++k) {
        const float dy = mf[(2 * k) * 256 + t];
        const float dx = mf[(2 * k + 1) * 256 + t];
        const float m  = mf[(18 + k) * 256 + t];
        const float py = (float)(y + k / 3 - 1) + dy;
        const float px = (float)(x + k % 3 - 1) + dx;

        const float y0f = floorf(py), x0f = floorf(px);
        const float wy = py - y0f, wx = px - x0f;
        const bool vy0 = (y0f >= 0.f) && (y0f <= 511.f);
        const bool vy1 = (y0f >= -1.f) && (y0f <= 510.f);
        const bool vx0 = (x0f >= 0.f) && (x0f <= 511.f);
        const bool vx1 = (x0f >= -1.f) && (x0f <= 510.f);
        const int iy0 = (int)fminf(fmaxf(y0f, 0.f), 511.f);
        const int iy1 = (int)fminf(fmaxf(y0f + 1.f, 0.f), 511.f);
        const int ix0 = (int)fminf(fmaxf(x0f, 0.f), 511.f);
        const int ix1 = (int)fminf(fmaxf(x0f + 1.f, 0.f), 511.f);
        const int lc  = (int)fminf(fmaxf(x0f, 0.f), 510.f);
        const int s0 = ix0 - lc, s1 = ix1 - lc;

        const float w00 = (vy0 && vx0) ? (1.f - wy) * (1.f - wx) * m : 0.f;
        const float w01 = (vy0 && vx1) ? (1.f - wy) * wx * m : 0.f;
        const float w10 = (vy1 && vx0) ? wy * (1.f - wx) * m : 0.f;
        const float w11 = (vy1 && vx1) ? wy * wx * m : 0.f;
        // Blend corner weights onto the two loaded pixel slots (clamp-safe).
        const float wlo0 = s0 ? 0.f : (s1 ? w00 : w00 + w01);
        const float whi0 = s1 ? (s0 ? w00 + w01 : w01) : 0.f;
        const float wlo1 = s0 ? 0.f : (s1 ? w10 : w10 + w11);
        const float whi1 = s1 ? (s0 ? w10 + w11 : w11) : 0.f;

        const unsigned off = ((unsigned)((iy0 << 9) | lc) << 1) | (unsigned)(iy1 != iy0);
        *(unsigned*)(tb + k * 1024 + t * 4) = off;
        *(__half2*)(tb + 9216 + k * 1024 + t * 4)  = __float22half2_rn(make_float2(wlo0, whi0));
        *(__half2*)(tb + 18432 + k * 1024 + t * 4) = __float22half2_rn(make_float2(wlo1, whi1));
    }
}

// LAST: fold out = (sharp + f1 + f2 + f3)/4 (pass 3).
template <bool LAST>
__global__ __launch_bounds__(256) void dcn_kernel(
    const uint2* __restrict__ src,     // [B][HWSZ] half4 px (current features)
    const char* __restrict__ taps,     // [NSTRIP][TAPB] precomputed taps
    const float* __restrict__ wgt,     // 81 floats [o][c][k]
    const float* __restrict__ bias,    // 3 floats
    uint2* __restrict__ dst,           // half4 px (if !LAST)
    const uint2* __restrict__ cS,      // sharp half4 (if LAST)
    const uint2* __restrict__ c1,      // f1 half4 (if LAST)
    float* __restrict__ out)           // [B,3,H,W] planar fp32 (if LAST)
{
    __shared__ __align__(16) char msmem[TAPB];   // 27648 B
    __shared__ float sw[84];

    const int t = threadIdx.x;
    const int blk = blockIdx.x;              // 4096
    const int b = blk >> 10;
    const int pbase = (blk & 1023) * 256;
    const int p = pbase + t;
    const int w = t >> 6, lane = t & 63;

    if (t < 84) sw[t] = (t < 81) ? wgt[t] : bias[t - 81];

    // DMA the 27648 B tap block -> LDS (27 chunks x 1024 B).
    {
        const char* tb = taps + (size_t)blk * TAPB;
#pragma unroll
        for (int r = 0; r < 7; ++r) {
            const int pl = r * 4 + w;
            if (pl < 27) {
                __builtin_amdgcn_global_load_lds((gas_t)(tb + pl * 1024 + lane * 16),
                                                 (las_t)(msmem + pl * 1024),
                                                 16, 0, 0);
            }
        }
    }

    const uint2* simg = src + ((size_t)b << 18);

    // Pass-3 center values (issued before the barrier to hide latency).
    U2 csv, c1v, c2v;
    if (LAST) {
        csv = *(const U2*)&cS[((size_t)b << 18) + p];
        c1v = *(const U2*)&c1[((size_t)b << 18) + p];
        c2v = *(const U2*)&simg[p];
    }

    __syncthreads();   // drains DMA (vmcnt+lgkmcnt)

    const char* sb = (const char*)simg;
    const unsigned* offs = (const unsigned*)msmem;
    const __half2* w0 = (const __half2*)(msmem + 9216);
    const __half2* w1 = (const __half2*)(msmem + 18432);

    float acc0 = sw[81], acc1 = sw[82], acc2 = sw[83];

#pragma unroll
    for (int k = 0; k < 9; ++k) {
        const unsigned off = offs[k * 256 + t];
        const float2 wA = __half22float2(w0[k * 256 + t]);   // (wlo0, whi0)
        const float2 wB = __half22float2(w1[k * 256 + t]);   // (wlo1, whi1)

        const char* pa = sb + (size_t)(off >> 1) * 8;
        U4 ra, rb;
        ra.u = *(const uint4*)(pa);                      // row iy0: lo px, hi px
        rb.u = *(const uint4*)(pa + (off & 1) * 4096);   // row iy1

        const float2 aL01 = __half22float2(ra.h[0]);
        const float2 aL2  = __half22float2(ra.h[1]);
        const float2 aH01 = __half22float2(ra.h[2]);
        const float2 aH2  = __half22float2(ra.h[3]);
        const float2 bL01 = __half22float2(rb.h[0]);
        const float2 bL2  = __half22float2(rb.h[1]);
        const float2 bH01 = __half22float2(rb.h[2]);
        const float2 bH2  = __half22float2(rb.h[3]);

        const float v0 = wA.x * aL01.x + wA.y * aH01.x + wB.x * bL01.x + wB.y * bH01.x;
        const float v1 = wA.x * aL01.y + wA.y * aH01.y + wB.x * bL01.y + wB.y * bH01.y;
        const float v2 = wA.x * aL2.x  + wA.y * aH2.x  + wB.x * bL2.x  + wB.y * bH2.x;

        acc0 += sw[0 * 9 + k] * v0 + sw[1 * 9 + k] * v1 + sw[2 * 9 + k] * v2;
        acc1 += sw[3 * 9 + k] * v0 + sw[4 * 9 + k] * v1 + sw[5 * 9 + k] * v2;
        acc2 += sw[6 * 9 + k] * v0 + sw[7 * 9 + k] * v1 + sw[8 * 9 + k] * v2;
    }

    if (!LAST) {
        U2 o;
        o.h[0] = __float22half2_rn(make_float2(acc0, acc1));
        o.h[1] = __float22half2_rn(make_float2(acc2, 0.f));
        dst[((size_t)b << 18) + p] = o.u;
    } else {
        const float2 s01 = __half22float2(csv.h[0]);
        const float2 s2  = __half22float2(csv.h[1]);
        const float2 a01 = __half22float2(c1v.h[0]);
        const float2 a2  = __half22float2(c1v.h[1]);
        const float2 b01 = __half22float2(c2v.h[0]);
        const float2 b2  = __half22float2(c2v.h[1]);
        const size_t ob = (size_t)b * 3 * HWSZ + p;
        out[ob]            = (s01.x + a01.x + b01.x + acc0) * 0.25f;
        out[ob + HWSZ]     = (s01.y + a01.y + b01.y + acc1) * 0.25f;
        out[ob + 2 * HWSZ] = (s2.x  + a2.x  + b2.x  + acc2) * 0.25f;
    }
}

extern "C" void kernel_launch(void* const* d_in, const int* in_sizes, int n_in,
                              void* d_out, int out_size, void* d_ws, size_t ws_size,
                              hipStream_t stream) {
    const float* sharp  = (const float*)d_in[0];
    const float* motion = (const float*)d_in[1];
    const float* wts    = (const float*)d_in[2];  // 3 x 81
    const float* bias   = (const float*)d_in[3];  // 3 x 3
    float* out = (float*)d_out;

    const size_t img = (size_t)BATCH * HWSZ;
    char* taps = (char*)d_ws;                      // 113.2 MB
    uint2* bufS = (uint2*)(taps + (size_t)NSTRIP * TAPB);   // 8.39 MB each
    uint2* buf1 = bufS + img;
    uint2* buf2 = buf1 + img;

    const dim3 block(256);
    const dim3 gridP(NSTRIP + 2048);               // taps + sharp conversion
    const dim3 gridD(NSTRIP);                      // 4096

    prep_kernel<<<gridP, block, 0, stream>>>(sharp, motion, (uint4*)bufS, taps);
    dcn_kernel<false><<<gridD, block, 0, stream>>>(
        bufS, taps, wts, bias, buf1, nullptr, nullptr, nullptr);
    dcn_kernel<false><<<gridD, block, 0, stream>>>(
        buf1, taps, wts + 81, bias + 3, buf2, nullptr, nullptr, nullptr);
    dcn_kernel<true><<<gridD, block, 0, stream>>>(
        buf2, taps, wts + 162, bias + 6, nullptr, bufS, buf1, out);
}